// Round 5
// baseline (274.730 us; speedup 1.0000x reference)
//
#include <hip/hip_runtime.h>

#define NIN 32
#define NU  128
#define RPB 4            // batch rows per block
#define NQ  4            // i-range quarters (threads per j)
#define UNFOLDS 6
#define LOG2E 1.44269504088896340736f

typedef float float4v __attribute__((ext_vector_type(4)));

#define SPN (NIN * NU)   // 4096 sensory synapses
#define RPN (NU * NU)    // 16384 recurrent synapses

// ---- prologue: pack (s2, sm2, We, Wv) per synapse ----
// exp(-sigma*(v-mu)) = 2^(s2*v + sm2),  s2 = -log2e*sigma, sm2 = -s2*mu
__global__ void pack_params(const float* __restrict__ mu,
                            const float* __restrict__ sig,
                            const float* __restrict__ W,
                            const float* __restrict__ erev,
                            float4v* __restrict__ out, int n) {
    int idx = blockIdx.x * blockDim.x + threadIdx.x;
    if (idx < n) {
        float sg = sig[idx];
        float s2 = -LOG2E * sg;
        float sm2 = -s2 * mu[idx];
        float Wv = W[idx];
        float We = Wv * erev[idx];
        out[idx] = (float4v){s2, sm2, We, Wv};
    }
}

// Pair-shared sigmoid for rows (r0,r1):
//   e_r = 2^(s2*v_r + sm2); a1 = 1+e1; P = fma(e0,a1,a1) = (1+e0)(1+e1)
//   rq = rcp(P); s0 = rq*a1; s1 = fma(rq,e0,rq)
// 1 exp2/eval + 0.5 rcp/eval, no staging array -> low live-register count.
#define EVAL_PAIR(p, v0, v1, n0, d0, n1, d1)                                   \
    {                                                                          \
        float e0 = __builtin_amdgcn_exp2f(__builtin_fmaf((p).x, (v0), (p).y)); \
        float e1 = __builtin_amdgcn_exp2f(__builtin_fmaf((p).x, (v1), (p).y)); \
        float a1 = 1.0f + e1;                                                  \
        float P  = __builtin_fmaf(e0, a1, a1);                                 \
        float rq = __builtin_amdgcn_rcpf(P);                                   \
        float s0 = rq * a1;                                                    \
        float s1 = __builtin_fmaf(rq, e0, rq);                                 \
        (n0) = __builtin_fmaf((p).z, s0, (n0));                                \
        (d0) = __builtin_fmaf((p).w, s0, (d0));                                \
        (n1) = __builtin_fmaf((p).z, s1, (n1));                                \
        (d1) = __builtin_fmaf((p).w, s1, (d1));                                \
    }

// block = 512 threads: j = tid&127 (unit), q = tid>>7 (i-quarter, wave-uniform).
// 4 batch rows per block; thread (j,q) accumulates num/den partials over its
// i-quarter for all 4 rows, partials reduced via LDS each unfold; thread
// (j,q) owns the v-update for row q. 8 waves/SIMD, ~40 live VGPRs.
__global__ __launch_bounds__(512, 8)
void wormnet_main(const float* __restrict__ inputs,   // [B,32]
                  const float* __restrict__ state,    // [B,128]
                  const float4v* __restrict__ sp,     // [32*128] packed
                  const float4v* __restrict__ rp,     // [128*128] packed
                  const float* __restrict__ vleak,
                  const float* __restrict__ gleak,
                  const float* __restrict__ cm_t,
                  const float* __restrict__ in_w, const float* __restrict__ in_b,
                  const float* __restrict__ out_w, const float* __restrict__ out_b,
                  float* __restrict__ out_y,          // [B]
                  float* __restrict__ out_v)          // [B,128]
{
    __shared__ __align__(16) float xs[NIN * RPB];     // xs[i*4 + r]    0.5 KB
    __shared__ __align__(16) float vs[NU * RPB];      // vs[i*4 + r]      2 KB
    __shared__ float rn[RPB][NQ][NU];                 // num partials     8 KB
    __shared__ float rd[RPB][NQ][NU];                 // den partials     8 KB

    const int tid  = threadIdx.x;
    const int j    = tid & (NU - 1);
    const int q    = tid >> 7;            // 0..3, wave-uniform
    const int base = blockIdx.x * RPB;

    // stage x = inputs*in_w + in_b (128 values; first 128 threads)
    if (tid < NIN * RPB) {
        int i = tid & (NIN - 1);
        int r = tid >> 5;
        xs[i * RPB + r] = inputs[(base + r) * NIN + i] * in_w[i] + in_b[i];
    }
    // stage initial v (512 values, 1 per thread: this thread's update row q)
    float vold = state[(base + q) * NU + j];
    vs[j * RPB + q] = vold;
    __syncthreads();

    // ---- sensory partial sums over i-quarter [q*8, q*8+8), all 4 rows ----
    float numS[RPB], denS[RPB];
    #pragma unroll
    for (int r = 0; r < RPB; ++r) { numS[r] = 0.0f; denS[r] = 0.0f; }
    {
        const float4v* pp = sp + q * (NIN / NQ) * NU + j;
        #pragma unroll 4
        for (int ii = 0; ii < NIN / NQ; ++ii) {
            const int i = q * (NIN / NQ) + ii;
            float4v p = pp[0]; pp += NU;
            float4v xv = *(const float4v*)&xs[i * RPB];
            EVAL_PAIR(p, xv[0], xv[1], numS[0], denS[0], numS[1], denS[1]);
            EVAL_PAIR(p, xv[2], xv[3], numS[2], denS[2], numS[3], denS[3]);
        }
    }

    // per-unit constants
    const float cm = cm_t[j];
    const float gl = gleak[j];
    const float glvl = gl * vleak[j];
    const float cg = cm + gl;

    // ---- 6 semi-implicit unfolds ----
    for (int u = 0; u < UNFOLDS; ++u) {
        float num[RPB], den[RPB];
        #pragma unroll
        for (int r = 0; r < RPB; ++r) { num[r] = numS[r]; den[r] = denS[r]; }

        const float4v* pp = rp + q * (NU / NQ) * NU + j;
        #pragma unroll 4
        for (int ii = 0; ii < NU / NQ; ++ii) {
            const int i = q * (NU / NQ) + ii;
            float4v p = pp[0]; pp += NU;
            float4v vv = *(const float4v*)&vs[i * RPB];
            EVAL_PAIR(p, vv[0], vv[1], num[0], den[0], num[1], den[1]);
            EVAL_PAIR(p, vv[2], vv[3], num[2], den[2], num[3], den[3]);
        }

        // publish partials (coalesced over j, conflict-free)
        #pragma unroll
        for (int r = 0; r < RPB; ++r) {
            rn[r][q][j] = num[r];
            rd[r][q][j] = den[r];
        }
        __syncthreads();

        // update this thread's row q
        {
            float tn = (rn[q][0][j] + rn[q][1][j]) + (rn[q][2][j] + rn[q][3][j]);
            float td = (rd[q][0][j] + rd[q][1][j]) + (rd[q][2][j] + rd[q][3][j]);
            float vn = (__builtin_fmaf(cm, vold, glvl) + tn)
                       * __builtin_amdgcn_rcpf(cg + td);
            vold = vn;
            vs[j * RPB + q] = vn;
        }
        __syncthreads();
    }

    // ---- epilogue: thread (j,q) writes its row (coalesced over j) ----
    out_v[(base + q) * NU + j] = vold;
    if (j == 0) {
        out_y[base + q] = __builtin_fmaf(vold, out_w[0], out_b[0]);
    }
}

extern "C" void kernel_launch(void* const* d_in, const int* in_sizes, int n_in,
                              void* d_out, int out_size, void* d_ws, size_t ws_size,
                              hipStream_t stream) {
    const float* inputs  = (const float*)d_in[0];
    const float* state   = (const float*)d_in[1];
    const float* smu     = (const float*)d_in[2];
    const float* ssig    = (const float*)d_in[3];
    const float* sW      = (const float*)d_in[4];
    const float* serev   = (const float*)d_in[5];
    const float* rmu     = (const float*)d_in[6];
    const float* rsig    = (const float*)d_in[7];
    const float* rW      = (const float*)d_in[8];
    const float* rerev   = (const float*)d_in[9];
    const float* vleak   = (const float*)d_in[10];
    const float* gleak   = (const float*)d_in[11];
    const float* cm_t    = (const float*)d_in[12];
    const float* in_w    = (const float*)d_in[13];
    const float* in_b    = (const float*)d_in[14];
    const float* out_w   = (const float*)d_in[15];
    const float* out_b   = (const float*)d_in[16];

    const int batch = in_sizes[1] / NU;        // 8192
    float* out_y = (float*)d_out;              // [batch]
    float* out_v = (float*)d_out + batch;      // [batch,128]

    float4v* sp = (float4v*)d_ws;
    float4v* rp = sp + SPN;

    hipLaunchKernelGGL(pack_params, dim3((SPN + 255) / 256), dim3(256), 0, stream,
                       smu, ssig, sW, serev, sp, SPN);
    hipLaunchKernelGGL(pack_params, dim3((RPN + 255) / 256), dim3(256), 0, stream,
                       rmu, rsig, rW, rerev, rp, RPN);

    dim3 grid(batch / RPB), block(NU * NQ);    // 2048 x 512
    hipLaunchKernelGGL(wormnet_main, grid, block, 0, stream,
                       inputs, state, sp, rp,
                       vleak, gleak, cm_t, in_w, in_b, out_w, out_b,
                       out_y, out_v);
}